// Round 1
// baseline (1393.249 us; speedup 1.0000x reference)
//
#include <hip/hip_runtime.h>

typedef __attribute__((ext_vector_type(8))) short short8;
typedef __attribute__((ext_vector_type(4))) short short4v;
typedef __attribute__((ext_vector_type(4))) float float4v;

#define B_ 4
#define H_ 16
#define S_ 2048
#define D_ 128
#define BM 64      // q rows per block
#define BN 64      // k cols per tile
#define NKT (S_ / BN)
#define LQK 136    // padded row length (shorts) for Qs/Ks: 272B -> stride 4 (mod 32) dwords
#define LVT 72     // padded row length (shorts) for VTs/Ps: 144B

// fp32 -> bf16 bits, round-to-nearest-even (inputs are finite)
__device__ __forceinline__ short f2bf(float f) {
  unsigned u = __float_as_uint(f);
  u = (u + 0x7fffu + ((u >> 16) & 1u)) >> 16;
  return (short)u;
}

__global__ __launch_bounds__(256, 3) void sdpa_kernel(
    const float* __restrict__ Qg, const float* __restrict__ Kg,
    const float* __restrict__ Vg, const int* __restrict__ Mg,
    float* __restrict__ Og, float* __restrict__ Ag) {

  // LDS: Ks persistent; Qs (pass-0 only) unions with VTs+Ps (pass-2 only)
  __shared__ __align__(16) char smem[17408 + 27648];
  short (*Ks)[LQK]  = (short (*)[LQK])(smem);
  short (*Qs)[LQK]  = (short (*)[LQK])(smem + 17408);
  short (*VTs)[LVT] = (short (*)[LVT])(smem + 17408);
  short (*Ps)[LVT]  = (short (*)[LVT])(smem + 17408 + 18432);

  const int t = threadIdx.x;
  const int w = t >> 6;        // wave 0..3
  const int l = t & 63;
  const int g = l >> 4;        // lane group 0..3
  const int c = l & 15;        // lane col 0..15 (this lane's q within the wave)

  const int bid = blockIdx.x;
  const int qt = bid & 31;           // S_/BM = 32 q-tiles
  const int h  = (bid >> 5) & 15;
  const int b  = bid >> 9;

  const int qbase  = qt * BM;
  const int qrow_l = w * 16 + c;     // local q row (0..63)
  const int qrow   = qbase + qrow_l; // global q row

  const size_t bhOff = (size_t)(b * H_ + h) * (S_ * D_);
  const float* Qp = Qg + bhOff;
  const float* Kp = Kg + bhOff;
  const float* Vp = Vg + bhOff;
  const int*   Mp = Mg + (size_t)b * S_ * S_;
  float* Op = Og + bhOff;
  float* Ap = Ag + (size_t)(b * H_ + h) * ((size_t)S_ * S_);

  // fold 1/sqrt(128) and log2(e) into Q: softmax in exp2 domain is identical
  constexpr float QSCALE = 0.08838834764831845f * 1.4426950408889634f;

  // ---------------- stage Q (scaled, bf16) ----------------
#pragma unroll
  for (int i = 0; i < 8; ++i) {
    int idx = t + i * 256;
    int d4 = idx & 31, row = idx >> 5;
    float4v v = *(const float4v*)(Qp + (size_t)(qbase + row) * D_ + d4 * 4);
    short4v s;
    s[0] = f2bf(v[0] * QSCALE);
    s[1] = f2bf(v[1] * QSCALE);
    s[2] = f2bf(v[2] * QSCALE);
    s[3] = f2bf(v[3] * QSCALE);
    *(short4v*)&Qs[row][d4 * 4] = s;
  }
  __syncthreads();

  // hoist this lane's Q fragments (B-operand: B[k_in][q], q = c, d contiguous)
  short8 qf[4];
#pragma unroll
  for (int dc = 0; dc < 4; ++dc)
    qf[dc] = *(const short8*)&Qs[qrow_l][dc * 32 + g * 8];

  // ---------------- pass 1: online row max + sum (log2 domain) ----------------
  float m_run = -1e30f, l_run = 0.f;
  for (int kt = 0; kt < NKT; ++kt) {
    __syncthreads();
#pragma unroll
    for (int i = 0; i < 8; ++i) {
      int idx = t + i * 256;
      int d4 = idx & 31, row = idx >> 5;
      float4v v = *(const float4v*)(Kp + (size_t)(kt * BN + row) * D_ + d4 * 4);
      short4v s;
      s[0] = f2bf(v[0]); s[1] = f2bf(v[1]); s[2] = f2bf(v[2]); s[3] = f2bf(v[3]);
      *(short4v*)&Ks[row][d4 * 4] = s;
    }
    __syncthreads();

    float4v acc[4];
#pragma unroll
    for (int kf = 0; kf < 4; ++kf) acc[kf] = (float4v){0.f, 0.f, 0.f, 0.f};
#pragma unroll
    for (int kf = 0; kf < 4; ++kf) {
#pragma unroll
      for (int dc = 0; dc < 4; ++dc) {
        short8 af = *(const short8*)&Ks[kf * 16 + c][dc * 32 + g * 8];
        acc[kf] = __builtin_amdgcn_mfma_f32_16x16x32_bf16(af, qf[dc], acc[kf], 0, 0, 0);
      }
    }

    // lane holds S[q=c][k = kt*64 + kf*16 + g*4 + r] (already log2-scaled)
    float sv[4][4];
    float tmax = -1e30f;
#pragma unroll
    for (int kf = 0; kf < 4; ++kf) {
      int k0 = kt * BN + kf * 16 + g * 4;
      const int4 mv = *(const int4*)(Mp + (size_t)qrow * S_ + k0);
      int mr[4] = {mv.x, mv.y, mv.z, mv.w};
#pragma unroll
      for (int r = 0; r < 4; ++r) {
        float x = acc[kf][r];
        x = (mr[r] == 0) ? -1e9f : x;
        sv[kf][r] = x;
        tmax = fmaxf(tmax, x);
      }
    }
    tmax = fmaxf(tmax, __shfl_xor(tmax, 16));
    tmax = fmaxf(tmax, __shfl_xor(tmax, 32));
    float newm = fmaxf(m_run, tmax);
    float tsum = 0.f;
#pragma unroll
    for (int kf = 0; kf < 4; ++kf)
#pragma unroll
      for (int r = 0; r < 4; ++r)
        tsum += __builtin_amdgcn_exp2f(sv[kf][r] - newm);
    tsum += __shfl_xor(tsum, 16);
    tsum += __shfl_xor(tsum, 32);
    l_run = l_run * __builtin_amdgcn_exp2f(m_run - newm) + tsum;
    m_run = newm;
  }

  const float rl = 1.0f / l_run;

  // ---------------- pass 2: attention write + PV ----------------
  float4v acco[8];
#pragma unroll
  for (int df = 0; df < 8; ++df) acco[df] = (float4v){0.f, 0.f, 0.f, 0.f};

  for (int kt = 0; kt < NKT; ++kt) {
    __syncthreads();
    // stage K
#pragma unroll
    for (int i = 0; i < 8; ++i) {
      int idx = t + i * 256;
      int d4 = idx & 31, row = idx >> 5;
      float4v v = *(const float4v*)(Kp + (size_t)(kt * BN + row) * D_ + d4 * 4);
      short4v s;
      s[0] = f2bf(v[0]); s[1] = f2bf(v[1]); s[2] = f2bf(v[2]); s[3] = f2bf(v[3]);
      *(short4v*)&Ks[row][d4 * 4] = s;
    }
    // stage V transposed: VTs[d][k] (coalesced 4B global reads along d)
#pragma unroll
    for (int i = 0; i < 8; ++i) {
      int idx = t + i * 256;
      int d = idx & 127, kq = idx >> 7;
      const float* vp = Vp + (size_t)(kt * BN + kq * 4) * D_ + d;
      short4v s;
      s[0] = f2bf(vp[0]);
      s[1] = f2bf(vp[D_]);
      s[2] = f2bf(vp[2 * D_]);
      s[3] = f2bf(vp[3 * D_]);
      *(short4v*)&VTs[d][kq * 4] = s;
    }
    __syncthreads();

    float4v acc[4];
#pragma unroll
    for (int kf = 0; kf < 4; ++kf) acc[kf] = (float4v){0.f, 0.f, 0.f, 0.f};
#pragma unroll
    for (int kf = 0; kf < 4; ++kf) {
#pragma unroll
      for (int dc = 0; dc < 4; ++dc) {
        short8 af = *(const short8*)&Ks[kf * 16 + c][dc * 32 + g * 8];
        acc[kf] = __builtin_amdgcn_mfma_f32_16x16x32_bf16(af, qf[dc], acc[kf], 0, 0, 0);
      }
    }

    // normalized probabilities: fp32 attention write + bf16 into Ps for PV
#pragma unroll
    for (int kf = 0; kf < 4; ++kf) {
      int k0 = kt * BN + kf * 16 + g * 4;
      const int4 mv = *(const int4*)(Mp + (size_t)qrow * S_ + k0);
      int mr[4] = {mv.x, mv.y, mv.z, mv.w};
      float4v aw;
      short4v pb;
#pragma unroll
      for (int r = 0; r < 4; ++r) {
        float x = acc[kf][r];
        x = (mr[r] == 0) ? -1e9f : x;
        float pn = __builtin_amdgcn_exp2f(x - m_run) * rl;
        aw[r] = pn;
        pb[r] = f2bf(pn);
      }
      __builtin_nontemporal_store(aw, (float4v*)(Ap + (size_t)qrow * S_ + k0));
      *(short4v*)&Ps[qrow_l][kf * 16 + g * 4] = pb;
    }

    // PV: O^T[d][q] += V^T[d][k] * P^T[k][q]  (Ps round-trip is wave-private)
#pragma unroll
    for (int kc = 0; kc < 2; ++kc) {
      short8 pbf = *(const short8*)&Ps[qrow_l][kc * 32 + g * 8];
#pragma unroll
      for (int df = 0; df < 8; ++df) {
        short8 vf = *(const short8*)&VTs[df * 16 + c][kc * 32 + g * 8];
        acco[df] = __builtin_amdgcn_mfma_f32_16x16x32_bf16(vf, pbf, acco[df], 0, 0, 0);
      }
    }
  }

  // ---------------- write O (lane holds O[q=c][d = df*16 + g*4 + r]) ----------------
#pragma unroll
  for (int df = 0; df < 8; ++df) {
    *(float4v*)(Op + (size_t)qrow * D_ + df * 16 + g * 4) = acco[df];
  }
}

extern "C" void kernel_launch(void* const* d_in, const int* in_sizes, int n_in,
                              void* d_out, int out_size, void* d_ws, size_t ws_size,
                              hipStream_t stream) {
  const float* Q = (const float*)d_in[0];
  const float* K = (const float*)d_in[1];
  const float* V = (const float*)d_in[2];
  const int*   M = (const int*)d_in[3];
  float* Out  = (float*)d_out;
  float* Attn = Out + (size_t)B_ * H_ * S_ * D_;
  sdpa_kernel<<<dim3(B_ * H_ * (S_ / BM)), dim3(256), 0, stream>>>(Q, K, V, M, Out, Attn);
}

// Round 2
// 877.861 us; speedup vs baseline: 1.5871x; 1.5871x over previous
//
#include <hip/hip_runtime.h>

typedef __attribute__((ext_vector_type(8))) short short8;
typedef __attribute__((ext_vector_type(4))) short short4v;
typedef __attribute__((ext_vector_type(4))) float float4v;

#define B_ 4
#define H_ 16
#define S_ 2048
#define D_ 128
#define BM 64
#define BN 64
#define NKT (S_ / BN)

#define NSH (B_ * H_ * S_ * D_)                 // shorts per converted tensor
#define WS_NEED (3ull * (unsigned long long)NSH * 2ull)

// fold 1/sqrt(128) and log2(e) into Q: softmax in exp2 domain is identical
#define QSCALE (0.08838834764831845f * 1.4426950408889634f)

// fp32 -> bf16 bits, round-to-nearest-even (inputs are finite)
__device__ __forceinline__ short f2bf(float f) {
  unsigned u = __float_as_uint(f);
  u = (u + 0x7fffu + ((u >> 16) & 1u)) >> 16;
  return (short)u;
}

// ---------------- pre-pass: Q scaled bf16, row-major ----------------
__global__ void prep_q(const float* __restrict__ Qg, short* __restrict__ Qb) {
  size_t id = (size_t)blockIdx.x * 256 + threadIdx.x;  // one per 8 elements
  const float4v* src = (const float4v*)(Qg + id * 8);
  float4v a = src[0], b = src[1];
  short8 s;
  s[0] = f2bf(a[0] * QSCALE); s[1] = f2bf(a[1] * QSCALE);
  s[2] = f2bf(a[2] * QSCALE); s[3] = f2bf(a[3] * QSCALE);
  s[4] = f2bf(b[0] * QSCALE); s[5] = f2bf(b[1] * QSCALE);
  s[6] = f2bf(b[2] * QSCALE); s[7] = f2bf(b[3] * QSCALE);
  *((short8*)Qb + id) = s;
}

// ---------------- pre-pass: K in MFMA A-fragment order ----------------
// layout: [bh][kt(32)][kf(4)][dc(4)][lane(64)][8], lane = g*16+c
// element = K[bh][kt*64 + kf*16 + c][dc*32 + g*8 + e]
__global__ void prep_k(const float* __restrict__ Kg, short* __restrict__ Kf) {
  size_t id = (size_t)blockIdx.x * 256 + threadIdx.x;
  int c  = (int)(id & 15);
  int g  = (int)((id >> 4) & 3);
  int dc = (int)((id >> 6) & 3);
  int kf = (int)((id >> 8) & 3);
  int kt = (int)((id >> 10) & 31);
  size_t bh = id >> 15;
  const float* src = Kg + ((bh * S_ + (size_t)(kt * 64 + kf * 16 + c)) * D_) + dc * 32 + g * 8;
  float4v a = *(const float4v*)src;
  float4v b = *(const float4v*)(src + 4);
  short8 s;
  s[0] = f2bf(a[0]); s[1] = f2bf(a[1]); s[2] = f2bf(a[2]); s[3] = f2bf(a[3]);
  s[4] = f2bf(b[0]); s[5] = f2bf(b[1]); s[6] = f2bf(b[2]); s[7] = f2bf(b[3]);
  *((short8*)Kf + id) = s;
}

// ---------------- pre-pass: V^T in MFMA A-fragment order ----------------
// layout: [bh][kt(32)][df(8)][kc(2)][lane(64)][8], lane = g*16+c
// element = V[bh][kt*64 + kc*32 + g*8 + e][df*16 + c]
__global__ void prep_v(const float* __restrict__ Vg, short* __restrict__ Vf) {
  size_t id = (size_t)blockIdx.x * 256 + threadIdx.x;
  int c  = (int)(id & 15);
  int g  = (int)((id >> 4) & 3);
  int kc = (int)((id >> 6) & 1);
  int df = (int)((id >> 7) & 7);
  int kt = (int)((id >> 10) & 31);
  size_t bh = id >> 15;
  const float* src = Vg + (bh * S_ + (size_t)(kt * 64 + kc * 32 + g * 8)) * D_ + df * 16 + c;
  short8 s;
#pragma unroll
  for (int e = 0; e < 8; ++e) s[e] = f2bf(src[(size_t)e * D_]);
  *((short8*)Vf + id) = s;
}

// ---------------- main: barrier-free 2-pass attention ----------------
__global__ __launch_bounds__(256, 4) void sdpa_main(
    const short* __restrict__ Qb, const short* __restrict__ Kfr,
    const short* __restrict__ Vfr, const int* __restrict__ Mg,
    float* __restrict__ Og, float* __restrict__ Ag) {

  __shared__ short Ps[64][72];   // wave-private P transpose (wave w owns rows w*16..w*16+15)

  const int t = threadIdx.x;
  const int w = t >> 6;
  const int l = t & 63;
  const int g = l >> 4;
  const int c = l & 15;

  const int bid = blockIdx.x;
  const int qt = bid & 31;
  const int h  = (bid >> 5) & 15;
  const int b  = bid >> 9;

  const int qbase  = qt * BM;
  const int qrow_l = w * 16 + c;
  const int qrow   = qbase + qrow_l;

  const size_t bhOff = (size_t)(b * H_ + h) * (S_ * D_);
  const short* Qp  = Qb  + bhOff;
  const short* Kp  = Kfr + bhOff;
  const short* Vp  = Vfr + bhOff;
  const int*   Mp  = Mg + (size_t)b * S_ * S_;
  float* Op = Og + bhOff;
  float* Ap = Ag + (size_t)(b * H_ + h) * ((size_t)S_ * S_);

  // per-lane Q fragments straight from global (already scaled bf16)
  short8 qf[4];
#pragma unroll
  for (int dc = 0; dc < 4; ++dc)
    qf[dc] = *(const short8*)(Qp + (size_t)qrow * D_ + dc * 32 + g * 8);

  // ---------------- pass 1: online row max + sum (log2 domain) ----------------
  float m_run = -1e30f, l_run = 0.f;
  for (int kt = 0; kt < NKT; ++kt) {
    const short* kb = Kp + (size_t)kt * (16 * 512);  // 16 frags x 512 shorts
    float4v acc[4];
#pragma unroll
    for (int kf = 0; kf < 4; ++kf) acc[kf] = (float4v){0.f, 0.f, 0.f, 0.f};
#pragma unroll
    for (int kf = 0; kf < 4; ++kf) {
#pragma unroll
      for (int dc = 0; dc < 4; ++dc) {
        short8 af = *(const short8*)(kb + ((kf * 4 + dc) * 64 + l) * 8);
        acc[kf] = __builtin_amdgcn_mfma_f32_16x16x32_bf16(af, qf[dc], acc[kf], 0, 0, 0);
      }
    }

    // lane holds S^T[k = kt*64 + kf*16 + g*4 + r][q = c]
    float sv[4][4];
    float tmax = -1e30f;
#pragma unroll
    for (int kf = 0; kf < 4; ++kf) {
      int k0 = kt * BN + kf * 16 + g * 4;
      const int4 mv = *(const int4*)(Mp + (size_t)qrow * S_ + k0);
      int mr[4] = {mv.x, mv.y, mv.z, mv.w};
#pragma unroll
      for (int r = 0; r < 4; ++r) {
        float x = acc[kf][r];
        x = (mr[r] == 0) ? -1e9f : x;
        sv[kf][r] = x;
        tmax = fmaxf(tmax, x);
      }
    }
    tmax = fmaxf(tmax, __shfl_xor(tmax, 16));
    tmax = fmaxf(tmax, __shfl_xor(tmax, 32));
    float newm = fmaxf(m_run, tmax);
    float tsum = 0.f;
#pragma unroll
    for (int kf = 0; kf < 4; ++kf)
#pragma unroll
      for (int r = 0; r < 4; ++r)
        tsum += __builtin_amdgcn_exp2f(sv[kf][r] - newm);
    tsum += __shfl_xor(tsum, 16);
    tsum += __shfl_xor(tsum, 32);
    l_run = l_run * __builtin_amdgcn_exp2f(m_run - newm) + tsum;
    m_run = newm;
  }

  const float rl = 1.0f / l_run;

  // ---------------- pass 2: attention write + PV ----------------
  float4v acco[8];
#pragma unroll
  for (int df = 0; df < 8; ++df) acco[df] = (float4v){0.f, 0.f, 0.f, 0.f};

  for (int kt = 0; kt < NKT; ++kt) {
    const short* kb = Kp + (size_t)kt * (16 * 512);
    const short* vb = Vp + (size_t)kt * (16 * 512);

    float4v acc[4];
#pragma unroll
    for (int kf = 0; kf < 4; ++kf) acc[kf] = (float4v){0.f, 0.f, 0.f, 0.f};
#pragma unroll
    for (int kf = 0; kf < 4; ++kf) {
#pragma unroll
      for (int dc = 0; dc < 4; ++dc) {
        short8 af = *(const short8*)(kb + ((kf * 4 + dc) * 64 + l) * 8);
        acc[kf] = __builtin_amdgcn_mfma_f32_16x16x32_bf16(af, qf[dc], acc[kf], 0, 0, 0);
      }
    }

    // normalized probabilities: fp32 attention write + bf16 into Ps for PV
#pragma unroll
    for (int kf = 0; kf < 4; ++kf) {
      int k0 = kt * BN + kf * 16 + g * 4;
      const int4 mv = *(const int4*)(Mp + (size_t)qrow * S_ + k0);
      int mr[4] = {mv.x, mv.y, mv.z, mv.w};
      float4v aw;
      short4v pb;
#pragma unroll
      for (int r = 0; r < 4; ++r) {
        float x = acc[kf][r];
        x = (mr[r] == 0) ? -1e9f : x;
        float pn = __builtin_amdgcn_exp2f(x - m_run) * rl;
        aw[r] = pn;
        pb[r] = f2bf(pn);
      }
      __builtin_nontemporal_store(aw, (float4v*)(Ap + (size_t)qrow * S_ + k0));
      *(short4v*)&Ps[qrow_l][kf * 16 + g * 4] = pb;
    }

    // PV: O^T[d][q] += V^T[d][k] * P^T[k][q]; Ps roundtrip is wave-private
#pragma unroll
    for (int kc = 0; kc < 2; ++kc) {
      short8 pbf = *(const short8*)&Ps[qrow_l][kc * 32 + g * 8];
#pragma unroll
      for (int df = 0; df < 8; ++df) {
        short8 vf = *(const short8*)(vb + ((df * 2 + kc) * 64 + l) * 8);
        acco[df] = __builtin_amdgcn_mfma_f32_16x16x32_bf16(vf, pbf, acco[df], 0, 0, 0);
      }
    }
  }

#pragma unroll
  for (int df = 0; df < 8; ++df) {
    *(float4v*)(Op + (size_t)qrow * D_ + df * 16 + g * 4) = acco[df];
  }
}

// ================= fallback (round-1 kernel) if ws too small =================
#define LQK 136
#define LVT 72

__global__ __launch_bounds__(256, 3) void sdpa_fallback(
    const float* __restrict__ Qg, const float* __restrict__ Kg,
    const float* __restrict__ Vg, const int* __restrict__ Mg,
    float* __restrict__ Og, float* __restrict__ Ag) {

  __shared__ __align__(16) char smem[17408 + 27648];
  short (*Ks)[LQK]  = (short (*)[LQK])(smem);
  short (*Qs)[LQK]  = (short (*)[LQK])(smem + 17408);
  short (*VTs)[LVT] = (short (*)[LVT])(smem + 17408);
  short (*Ps)[LVT]  = (short (*)[LVT])(smem + 17408 + 18432);

  const int t = threadIdx.x;
  const int w = t >> 6;
  const int l = t & 63;
  const int g = l >> 4;
  const int c = l & 15;

  const int bid = blockIdx.x;
  const int qt = bid & 31;
  const int h  = (bid >> 5) & 15;
  const int b  = bid >> 9;

  const int qbase  = qt * BM;
  const int qrow_l = w * 16 + c;
  const int qrow   = qbase + qrow_l;

  const size_t bhOff = (size_t)(b * H_ + h) * (S_ * D_);
  const float* Qp = Qg + bhOff;
  const float* Kp = Kg + bhOff;
  const float* Vp = Vg + bhOff;
  const int*   Mp = Mg + (size_t)b * S_ * S_;
  float* Op = Og + bhOff;
  float* Ap = Ag + (size_t)(b * H_ + h) * ((size_t)S_ * S_);

#pragma unroll
  for (int i = 0; i < 8; ++i) {
    int idx = t + i * 256;
    int d4 = idx & 31, row = idx >> 5;
    float4v v = *(const float4v*)(Qp + (size_t)(qbase + row) * D_ + d4 * 4);
    short4v s;
    s[0] = f2bf(v[0] * QSCALE); s[1] = f2bf(v[1] * QSCALE);
    s[2] = f2bf(v[2] * QSCALE); s[3] = f2bf(v[3] * QSCALE);
    *(short4v*)&Qs[row][d4 * 4] = s;
  }
  __syncthreads();

  short8 qf[4];
#pragma unroll
  for (int dc = 0; dc < 4; ++dc)
    qf[dc] = *(const short8*)&Qs[qrow_l][dc * 32 + g * 8];

  float m_run = -1e30f, l_run = 0.f;
  for (int kt = 0; kt < NKT; ++kt) {
    __syncthreads();
#pragma unroll
    for (int i = 0; i < 8; ++i) {
      int idx = t + i * 256;
      int d4 = idx & 31, row = idx >> 5;
      float4v v = *(const float4v*)(Kp + (size_t)(kt * BN + row) * D_ + d4 * 4);
      short4v s;
      s[0] = f2bf(v[0]); s[1] = f2bf(v[1]); s[2] = f2bf(v[2]); s[3] = f2bf(v[3]);
      *(short4v*)&Ks[row][d4 * 4] = s;
    }
    __syncthreads();

    float4v acc[4];
#pragma unroll
    for (int kf = 0; kf < 4; ++kf) acc[kf] = (float4v){0.f, 0.f, 0.f, 0.f};
#pragma unroll
    for (int kf = 0; kf < 4; ++kf) {
#pragma unroll
      for (int dc = 0; dc < 4; ++dc) {
        short8 af = *(const short8*)&Ks[kf * 16 + c][dc * 32 + g * 8];
        acc[kf] = __builtin_amdgcn_mfma_f32_16x16x32_bf16(af, qf[dc], acc[kf], 0, 0, 0);
      }
    }

    float sv[4][4];
    float tmax = -1e30f;
#pragma unroll
    for (int kf = 0; kf < 4; ++kf) {
      int k0 = kt * BN + kf * 16 + g * 4;
      const int4 mv = *(const int4*)(Mp + (size_t)qrow * S_ + k0);
      int mr[4] = {mv.x, mv.y, mv.z, mv.w};
#pragma unroll
      for (int r = 0; r < 4; ++r) {
        float x = acc[kf][r];
        x = (mr[r] == 0) ? -1e9f : x;
        sv[kf][r] = x;
        tmax = fmaxf(tmax, x);
      }
    }
    tmax = fmaxf(tmax, __shfl_xor(tmax, 16));
    tmax = fmaxf(tmax, __shfl_xor(tmax, 32));
    float newm = fmaxf(m_run, tmax);
    float tsum = 0.f;
#pragma unroll
    for (int kf = 0; kf < 4; ++kf)
#pragma unroll
      for (int r = 0; r < 4; ++r)
        tsum += __builtin_amdgcn_exp2f(sv[kf][r] - newm);
    tsum += __shfl_xor(tsum, 16);
    tsum += __shfl_xor(tsum, 32);
    l_run = l_run * __builtin_amdgcn_exp2f(m_run - newm) + tsum;
    m_run = newm;
  }

  const float rl = 1.0f / l_run;

  float4v acco[8];
#pragma unroll
  for (int df = 0; df < 8; ++df) acco[df] = (float4v){0.f, 0.f, 0.f, 0.f};

  for (int kt = 0; kt < NKT; ++kt) {
    __syncthreads();
#pragma unroll
    for (int i = 0; i < 8; ++i) {
      int idx = t + i * 256;
      int d4 = idx & 31, row = idx >> 5;
      float4v v = *(const float4v*)(Kp + (size_t)(kt * BN + row) * D_ + d4 * 4);
      short4v s;
      s[0] = f2bf(v[0]); s[1] = f2bf(v[1]); s[2] = f2bf(v[2]); s[3] = f2bf(v[3]);
      *(short4v*)&Ks[row][d4 * 4] = s;
    }
#pragma unroll
    for (int i = 0; i < 8; ++i) {
      int idx = t + i * 256;
      int d = idx & 127, kq = idx >> 7;
      const float* vp = Vp + (size_t)(kt * BN + kq * 4) * D_ + d;
      short4v s;
      s[0] = f2bf(vp[0]); s[1] = f2bf(vp[D_]); s[2] = f2bf(vp[2 * D_]); s[3] = f2bf(vp[3 * D_]);
      *(short4v*)&VTs[d][kq * 4] = s;
    }
    __syncthreads();

    float4v acc[4];
#pragma unroll
    for (int kf = 0; kf < 4; ++kf) acc[kf] = (float4v){0.f, 0.f, 0.f, 0.f};
#pragma unroll
    for (int kf = 0; kf < 4; ++kf) {
#pragma unroll
      for (int dc = 0; dc < 4; ++dc) {
        short8 af = *(const short8*)&Ks[kf * 16 + c][dc * 32 + g * 8];
        acc[kf] = __builtin_amdgcn_mfma_f32_16x16x32_bf16(af, qf[dc], acc[kf], 0, 0, 0);
      }
    }

#pragma unroll
    for (int kf = 0; kf < 4; ++kf) {
      int k0 = kt * BN + kf * 16 + g * 4;
      const int4 mv = *(const int4*)(Mp + (size_t)qrow * S_ + k0);
      int mr[4] = {mv.x, mv.y, mv.z, mv.w};
      float4v aw;
      short4v pb;
#pragma unroll
      for (int r = 0; r < 4; ++r) {
        float x = acc[kf][r];
        x = (mr[r] == 0) ? -1e9f : x;
        float pn = __builtin_amdgcn_exp2f(x - m_run) * rl;
        aw[r] = pn;
        pb[r] = f2bf(pn);
      }
      __builtin_nontemporal_store(aw, (float4v*)(Ap + (size_t)qrow * S_ + k0));
      *(short4v*)&Ps[qrow_l][kf * 16 + g * 4] = pb;
    }

#pragma unroll
    for (int kc = 0; kc < 2; ++kc) {
      short8 pbf = *(const short8*)&Ps[qrow_l][kc * 32 + g * 8];
#pragma unroll
      for (int df = 0; df < 8; ++df) {
        short8 vf = *(const short8*)&VTs[df * 16 + c][kc * 32 + g * 8];
        acco[df] = __builtin_amdgcn_mfma_f32_16x16x32_bf16(vf, pbf, acco[df], 0, 0, 0);
      }
    }
  }

#pragma unroll
  for (int df = 0; df < 8; ++df) {
    *(float4v*)(Op + (size_t)qrow * D_ + df * 16 + g * 4) = acco[df];
  }
}

extern "C" void kernel_launch(void* const* d_in, const int* in_sizes, int n_in,
                              void* d_out, int out_size, void* d_ws, size_t ws_size,
                              hipStream_t stream) {
  const float* Q = (const float*)d_in[0];
  const float* K = (const float*)d_in[1];
  const float* V = (const float*)d_in[2];
  const int*   M = (const int*)d_in[3];
  float* Out  = (float*)d_out;
  float* Attn = Out + (size_t)B_ * H_ * S_ * D_;

  if (ws_size >= WS_NEED) {
    short* Qb = (short*)d_ws;
    short* Kf = Qb + (size_t)NSH;
    short* Vf = Kf + (size_t)NSH;
    const int pgrid = NSH / 8 / 256;  // 8192
    prep_q<<<dim3(pgrid), dim3(256), 0, stream>>>(Q, Qb);
    prep_k<<<dim3(pgrid), dim3(256), 0, stream>>>(K, Kf);
    prep_v<<<dim3(pgrid), dim3(256), 0, stream>>>(V, Vf);
    sdpa_main<<<dim3(B_ * H_ * (S_ / BM)), dim3(256), 0, stream>>>(Qb, Kf, Vf, M, Out, Attn);
  } else {
    sdpa_fallback<<<dim3(B_ * H_ * (S_ / BM)), dim3(256), 0, stream>>>(Q, K, V, M, Out, Attn);
  }
}

// Round 4
// 837.439 us; speedup vs baseline: 1.6637x; 1.0483x over previous
//
#include <hip/hip_runtime.h>

typedef __attribute__((ext_vector_type(8))) short short8;
typedef __attribute__((ext_vector_type(4))) short short4v;
typedef __attribute__((ext_vector_type(4))) float float4v;

#define B_ 4
#define H_ 16
#define S_ 2048
#define D_ 128
#define BM 64
#define BN 64
#define NKT (S_ / BN)

#define NSH (B_ * H_ * S_ * D_)                 // shorts per converted tensor
#define NMW ((size_t)B_ * 32 * S_)              // u64 mask words
#define WS_NEED (3ull * (unsigned long long)NSH * 2ull + (unsigned long long)NMW * 8ull)

// fold 1/sqrt(128) and log2(e) into Q: softmax in exp2 domain is identical
#define QSCALE (0.08838834764831845f * 1.4426950408889634f)

// fp32 -> bf16 bits, round-to-nearest-even (inputs are finite)
__device__ __forceinline__ short f2bf(float f) {
  unsigned u = __float_as_uint(f);
  u = (u + 0x7fffu + ((u >> 16) & 1u)) >> 16;
  return (short)u;
}

// ---------------- pre-pass: Q scaled bf16, row-major ----------------
__global__ void prep_q(const float* __restrict__ Qg, short* __restrict__ Qb) {
  size_t id = (size_t)blockIdx.x * 256 + threadIdx.x;  // one per 8 elements
  const float4v* src = (const float4v*)(Qg + id * 8);
  float4v a = src[0], b = src[1];
  short8 s;
  s[0] = f2bf(a[0] * QSCALE); s[1] = f2bf(a[1] * QSCALE);
  s[2] = f2bf(a[2] * QSCALE); s[3] = f2bf(a[3] * QSCALE);
  s[4] = f2bf(b[0] * QSCALE); s[5] = f2bf(b[1] * QSCALE);
  s[6] = f2bf(b[2] * QSCALE); s[7] = f2bf(b[3] * QSCALE);
  *((short8*)Qb + id) = s;
}

// ---------------- pre-pass: K in MFMA A-fragment order ----------------
// layout: [bh][kt(32)][kf(4)][dc(4)][lane(64)][8], lane = g*16+c
// element = K[bh][kt*64 + kf*16 + c][dc*32 + g*8 + e]
__global__ void prep_k(const float* __restrict__ Kg, short* __restrict__ Kf) {
  size_t id = (size_t)blockIdx.x * 256 + threadIdx.x;
  int c  = (int)(id & 15);
  int g  = (int)((id >> 4) & 3);
  int dc = (int)((id >> 6) & 3);
  int kf = (int)((id >> 8) & 3);
  int kt = (int)((id >> 10) & 31);
  size_t bh = id >> 15;
  const float* src = Kg + ((bh * S_ + (size_t)(kt * 64 + kf * 16 + c)) * D_) + dc * 32 + g * 8;
  float4v a = *(const float4v*)src;
  float4v b = *(const float4v*)(src + 4);
  short8 s;
  s[0] = f2bf(a[0]); s[1] = f2bf(a[1]); s[2] = f2bf(a[2]); s[3] = f2bf(a[3]);
  s[4] = f2bf(b[0]); s[5] = f2bf(b[1]); s[6] = f2bf(b[2]); s[7] = f2bf(b[3]);
  *((short8*)Kf + id) = s;
}

// ---------------- pre-pass: V^T in MFMA A-fragment order ----------------
// layout: [bh][kt(32)][df(8)][kc(2)][lane(64)][8], lane = g*16+c
// element = V[bh][kt*64 + kc*32 + g*8 + e][df*16 + c]
__global__ void prep_v(const float* __restrict__ Vg, short* __restrict__ Vf) {
  size_t id = (size_t)blockIdx.x * 256 + threadIdx.x;
  int c  = (int)(id & 15);
  int g  = (int)((id >> 4) & 3);
  int kc = (int)((id >> 6) & 1);
  int df = (int)((id >> 7) & 7);
  int kt = (int)((id >> 10) & 31);
  size_t bh = id >> 15;
  const float* src = Vg + (bh * S_ + (size_t)(kt * 64 + kc * 32 + g * 8)) * D_ + df * 16 + c;
  short8 s;
#pragma unroll
  for (int e = 0; e < 8; ++e) s[e] = f2bf(src[(size_t)e * D_]);
  *((short8*)Vf + id) = s;
}

// ---------------- pre-pass: bit-pack mask via ballot ----------------
// Bits[b][kt(32)][q(2048)] u64; bit j = (mask[b][q][kt*64+j] != 0)
// one wave per u64 word -> grid must cover NMW waves = NMW/4 blocks
__global__ void prep_m(const int* __restrict__ Mg, unsigned long long* __restrict__ Bits) {
  int gw = blockIdx.x * 4 + (threadIdx.x >> 6);   // global wave id, 0..NMW-1
  int j  = threadIdx.x & 63;
  int kt = gw & 31;
  int q  = (gw >> 5) & (S_ - 1);
  int b  = gw >> 16;
  int m = Mg[((size_t)b * S_ + q) * S_ + kt * 64 + j];
  unsigned long long bal = __ballot(m != 0);
  if (j == 0) Bits[((size_t)b * 32 + kt) * S_ + q] = bal;
}

// ---------------- main: barrier-free 2-pass attention, no-max softmax ----------------
__global__ __launch_bounds__(256, 5) void sdpa_main(
    const short* __restrict__ Qb, const short* __restrict__ Kfr,
    const short* __restrict__ Vfr, const unsigned long long* __restrict__ Bits,
    float* __restrict__ Og, float* __restrict__ Ag) {

  __shared__ short Ps[64][72];   // wave-private P transpose (wave w owns rows w*16..w*16+15)

  const int t = threadIdx.x;
  const int w = t >> 6;
  const int l = t & 63;
  const int g = l >> 4;
  const int c = l & 15;

  const int bid = blockIdx.x;
  const int qt = bid & 31;
  const int h  = (bid >> 5) & 15;
  const int b  = bid >> 9;

  const int qbase  = qt * BM;
  const int qrow_l = w * 16 + c;
  const int qrow   = qbase + qrow_l;

  const size_t bhOff = (size_t)(b * H_ + h) * (S_ * D_);
  const short* Qp  = Qb  + bhOff;
  const short* Kp  = Kfr + bhOff;
  const short* Vp  = Vfr + bhOff;
  const unsigned long long* Bp = Bits + (size_t)b * 32 * S_;
  float* Op = Og + bhOff;
  float* Ap = Ag + (size_t)(b * H_ + h) * ((size_t)S_ * S_);

  // per-lane Q fragments straight from global (already scaled bf16)
  short8 qf[4];
#pragma unroll
  for (int dc = 0; dc < 4; ++dc)
    qf[dc] = *(const short8*)(Qp + (size_t)qrow * D_ + dc * 32 + g * 8);

  // ------- pass 1: row sum of exp2(scores) — per-lane partials, no max, no shfl in loop -------
  float ls0 = 0.f, ls1 = 0.f, ls2 = 0.f, ls3 = 0.f;
  for (int kt = 0; kt < NKT; ++kt) {
    const short* kb = Kp + (size_t)kt * (16 * 512);  // 16 frags x 512 shorts
    unsigned long long mb = Bp[(size_t)kt * S_ + qrow];
    float4v acc[4];
#pragma unroll
    for (int kf = 0; kf < 4; ++kf) acc[kf] = (float4v){0.f, 0.f, 0.f, 0.f};
#pragma unroll
    for (int kf = 0; kf < 4; ++kf) {
#pragma unroll
      for (int dc = 0; dc < 4; ++dc) {
        short8 af = *(const short8*)(kb + ((kf * 4 + dc) * 64 + l) * 8);
        acc[kf] = __builtin_amdgcn_mfma_f32_16x16x32_bf16(af, qf[dc], acc[kf], 0, 0, 0);
      }
    }
    // lane holds S^T[k = kt*64 + kf*16 + g*4 + r][q = c] (log2 domain)
#pragma unroll
    for (int kf = 0; kf < 4; ++kf) {
      unsigned mg = (unsigned)(mb >> (kf * 16 + g * 4)) & 0xFu;
      float p0 = ((mg >> 0) & 1) ? __builtin_amdgcn_exp2f(acc[kf][0]) : 0.f;
      float p1 = ((mg >> 1) & 1) ? __builtin_amdgcn_exp2f(acc[kf][1]) : 0.f;
      float p2 = ((mg >> 2) & 1) ? __builtin_amdgcn_exp2f(acc[kf][2]) : 0.f;
      float p3 = ((mg >> 3) & 1) ? __builtin_amdgcn_exp2f(acc[kf][3]) : 0.f;
      if (kf == 0) ls0 += (p0 + p1) + (p2 + p3);
      else if (kf == 1) ls1 += (p0 + p1) + (p2 + p3);
      else if (kf == 2) ls2 += (p0 + p1) + (p2 + p3);
      else ls3 += (p0 + p1) + (p2 + p3);
    }
  }
  float lsum = (ls0 + ls1) + (ls2 + ls3);
  lsum += __shfl_xor(lsum, 16);
  lsum += __shfl_xor(lsum, 32);
  const float rl = (lsum > 0.f) ? (1.0f / lsum) : 0.f;

  // ---------------- pass 2: attention write + PV ----------------
  float4v acco[8];
#pragma unroll
  for (int df = 0; df < 8; ++df) acco[df] = (float4v){0.f, 0.f, 0.f, 0.f};

  for (int kt = 0; kt < NKT; ++kt) {
    const short* kb = Kp + (size_t)kt * (16 * 512);
    const short* vb = Vp + (size_t)kt * (16 * 512);
    unsigned long long mb = Bp[(size_t)kt * S_ + qrow];

    float4v acc[4];
#pragma unroll
    for (int kf = 0; kf < 4; ++kf) acc[kf] = (float4v){0.f, 0.f, 0.f, 0.f};
#pragma unroll
    for (int kf = 0; kf < 4; ++kf) {
#pragma unroll
      for (int dc = 0; dc < 4; ++dc) {
        short8 af = *(const short8*)(kb + ((kf * 4 + dc) * 64 + l) * 8);
        acc[kf] = __builtin_amdgcn_mfma_f32_16x16x32_bf16(af, qf[dc], acc[kf], 0, 0, 0);
      }
    }

    // normalized probabilities: fp32 attention write + bf16 into Ps for PV
#pragma unroll
    for (int kf = 0; kf < 4; ++kf) {
      int k0 = kt * BN + kf * 16 + g * 4;
      unsigned mg = (unsigned)(mb >> (kf * 16 + g * 4)) & 0xFu;
      float4v aw;
      short4v pb;
#pragma unroll
      for (int r = 0; r < 4; ++r) {
        float pn = ((mg >> r) & 1) ? __builtin_amdgcn_exp2f(acc[kf][r]) * rl : 0.f;
        aw[r] = pn;
        pb[r] = f2bf(pn);
      }
      __builtin_nontemporal_store(aw, (float4v*)(Ap + (size_t)qrow * S_ + k0));
      *(short4v*)&Ps[qrow_l][kf * 16 + g * 4] = pb;
    }

    // PV: O^T[d][q] += V^T[d][k] * P^T[k][q]; Ps roundtrip is wave-private
#pragma unroll
    for (int kc = 0; kc < 2; ++kc) {
      short8 pbf = *(const short8*)&Ps[qrow_l][kc * 32 + g * 8];
#pragma unroll
      for (int df = 0; df < 8; ++df) {
        short8 vf = *(const short8*)(vb + ((df * 2 + kc) * 64 + l) * 8);
        acco[df] = __builtin_amdgcn_mfma_f32_16x16x32_bf16(vf, pbf, acco[df], 0, 0, 0);
      }
    }
  }

#pragma unroll
  for (int df = 0; df < 8; ++df) {
    *(float4v*)(Op + (size_t)qrow * D_ + df * 16 + g * 4) = acco[df];
  }
}

// ================= fallback (round-1 kernel) if ws too small =================
#define LQK 136
#define LVT 72

__global__ __launch_bounds__(256, 3) void sdpa_fallback(
    const float* __restrict__ Qg, const float* __restrict__ Kg,
    const float* __restrict__ Vg, const int* __restrict__ Mg,
    float* __restrict__ Og, float* __restrict__ Ag) {

  __shared__ __align__(16) char smem[17408 + 27648];
  short (*Ks)[LQK]  = (short (*)[LQK])(smem);
  short (*Qs)[LQK]  = (short (*)[LQK])(smem + 17408);
  short (*VTs)[LVT] = (short (*)[LVT])(smem + 17408);
  short (*Ps)[LVT]  = (short (*)[LVT])(smem + 17408 + 18432);

  const int t = threadIdx.x;
  const int w = t >> 6;
  const int l = t & 63;
  const int g = l >> 4;
  const int c = l & 15;

  const int bid = blockIdx.x;
  const int qt = bid & 31;
  const int h  = (bid >> 5) & 15;
  const int b  = bid >> 9;

  const int qbase  = qt * BM;
  const int qrow_l = w * 16 + c;
  const int qrow   = qbase + qrow_l;

  const size_t bhOff = (size_t)(b * H_ + h) * (S_ * D_);
  const float* Qp = Qg + bhOff;
  const float* Kp = Kg + bhOff;
  const float* Vp = Vg + bhOff;
  const int*   Mp = Mg + (size_t)b * S_ * S_;
  float* Op = Og + bhOff;
  float* Ap = Ag + (size_t)(b * H_ + h) * ((size_t)S_ * S_);

#pragma unroll
  for (int i = 0; i < 8; ++i) {
    int idx = t + i * 256;
    int d4 = idx & 31, row = idx >> 5;
    float4v v = *(const float4v*)(Qp + (size_t)(qbase + row) * D_ + d4 * 4);
    short4v s;
    s[0] = f2bf(v[0] * QSCALE); s[1] = f2bf(v[1] * QSCALE);
    s[2] = f2bf(v[2] * QSCALE); s[3] = f2bf(v[3] * QSCALE);
    *(short4v*)&Qs[row][d4 * 4] = s;
  }
  __syncthreads();

  short8 qf[4];
#pragma unroll
  for (int dc = 0; dc < 4; ++dc)
    qf[dc] = *(const short8*)&Qs[qrow_l][dc * 32 + g * 8];

  float m_run = -1e30f, l_run = 0.f;
  for (int kt = 0; kt < NKT; ++kt) {
    __syncthreads();
#pragma unroll
    for (int i = 0; i < 8; ++i) {
      int idx = t + i * 256;
      int d4 = idx & 31, row = idx >> 5;
      float4v v = *(const float4v*)(Kp + (size_t)(kt * BN + row) * D_ + d4 * 4);
      short4v s;
      s[0] = f2bf(v[0]); s[1] = f2bf(v[1]); s[2] = f2bf(v[2]); s[3] = f2bf(v[3]);
      *(short4v*)&Ks[row][d4 * 4] = s;
    }
    __syncthreads();

    float4v acc[4];
#pragma unroll
    for (int kf = 0; kf < 4; ++kf) acc[kf] = (float4v){0.f, 0.f, 0.f, 0.f};
#pragma unroll
    for (int kf = 0; kf < 4; ++kf) {
#pragma unroll
      for (int dc = 0; dc < 4; ++dc) {
        short8 af = *(const short8*)&Ks[kf * 16 + c][dc * 32 + g * 8];
        acc[kf] = __builtin_amdgcn_mfma_f32_16x16x32_bf16(af, qf[dc], acc[kf], 0, 0, 0);
      }
    }

    float sv[4][4];
    float tmax = -1e30f;
#pragma unroll
    for (int kf = 0; kf < 4; ++kf) {
      int k0 = kt * BN + kf * 16 + g * 4;
      const int4 mv = *(const int4*)(Mp + (size_t)qrow * S_ + k0);
      int mr[4] = {mv.x, mv.y, mv.z, mv.w};
#pragma unroll
      for (int r = 0; r < 4; ++r) {
        float x = acc[kf][r];
        x = (mr[r] == 0) ? -1e9f : x;
        sv[kf][r] = x;
        tmax = fmaxf(tmax, x);
      }
    }
    tmax = fmaxf(tmax, __shfl_xor(tmax, 16));
    tmax = fmaxf(tmax, __shfl_xor(tmax, 32));
    float newm = fmaxf(m_run, tmax);
    float tsum = 0.f;
#pragma unroll
    for (int kf = 0; kf < 4; ++kf)
#pragma unroll
      for (int r = 0; r < 4; ++r)
        tsum += __builtin_amdgcn_exp2f(sv[kf][r] - newm);
    tsum += __shfl_xor(tsum, 16);
    tsum += __shfl_xor(tsum, 32);
    l_run = l_run * __builtin_amdgcn_exp2f(m_run - newm) + tsum;
    m_run = newm;
  }

  const float rl = 1.0f / l_run;

  float4v acco[8];
#pragma unroll
  for (int df = 0; df < 8; ++df) acco[df] = (float4v){0.f, 0.f, 0.f, 0.f};

  for (int kt = 0; kt < NKT; ++kt) {
    __syncthreads();
#pragma unroll
    for (int i = 0; i < 8; ++i) {
      int idx = t + i * 256;
      int d4 = idx & 31, row = idx >> 5;
      float4v v = *(const float4v*)(Kp + (size_t)(kt * BN + row) * D_ + d4 * 4);
      short4v s;
      s[0] = f2bf(v[0]); s[1] = f2bf(v[1]); s[2] = f2bf(v[2]); s[3] = f2bf(v[3]);
      *(short4v*)&Ks[row][d4 * 4] = s;
    }
#pragma unroll
    for (int i = 0; i < 8; ++i) {
      int idx = t + i * 256;
      int d = idx & 127, kq = idx >> 7;
      const float* vp = Vp + (size_t)(kt * BN + kq * 4) * D_ + d;
      short4v s;
      s[0] = f2bf(vp[0]); s[1] = f2bf(vp[D_]); s[2] = f2bf(vp[2 * D_]); s[3] = f2bf(vp[3 * D_]);
      *(short4v*)&VTs[d][kq * 4] = s;
    }
    __syncthreads();

    float4v acc[4];
#pragma unroll
    for (int kf = 0; kf < 4; ++kf) acc[kf] = (float4v){0.f, 0.f, 0.f, 0.f};
#pragma unroll
    for (int kf = 0; kf < 4; ++kf) {
#pragma unroll
      for (int dc = 0; dc < 4; ++dc) {
        short8 af = *(const short8*)&Ks[kf * 16 + c][dc * 32 + g * 8];
        acc[kf] = __builtin_amdgcn_mfma_f32_16x16x32_bf16(af, qf[dc], acc[kf], 0, 0, 0);
      }
    }

#pragma unroll
    for (int kf = 0; kf < 4; ++kf) {
      int k0 = kt * BN + kf * 16 + g * 4;
      const int4 mv = *(const int4*)(Mp + (size_t)qrow * S_ + k0);
      int mr[4] = {mv.x, mv.y, mv.z, mv.w};
      float4v aw;
      short4v pb;
#pragma unroll
      for (int r = 0; r < 4; ++r) {
        float x = acc[kf][r];
        x = (mr[r] == 0) ? -1e9f : x;
        float pn = __builtin_amdgcn_exp2f(x - m_run) * rl;
        aw[r] = pn;
        pb[r] = f2bf(pn);
      }
      __builtin_nontemporal_store(aw, (float4v*)(Ap + (size_t)qrow * S_ + k0));
      *(short4v*)&Ps[qrow_l][kf * 16 + g * 4] = pb;
    }

#pragma unroll
    for (int kc = 0; kc < 2; ++kc) {
      short8 pbf = *(const short8*)&Ps[qrow_l][kc * 32 + g * 8];
#pragma unroll
      for (int df = 0; df < 8; ++df) {
        short8 vf = *(const short8*)&VTs[df * 16 + c][kc * 32 + g * 8];
        acco[df] = __builtin_amdgcn_mfma_f32_16x16x32_bf16(vf, pbf, acco[df], 0, 0, 0);
      }
    }
  }

#pragma unroll
  for (int df = 0; df < 8; ++df) {
    *(float4v*)(Op + (size_t)qrow * D_ + df * 16 + g * 4) = acco[df];
  }
}

extern "C" void kernel_launch(void* const* d_in, const int* in_sizes, int n_in,
                              void* d_out, int out_size, void* d_ws, size_t ws_size,
                              hipStream_t stream) {
  const float* Q = (const float*)d_in[0];
  const float* K = (const float*)d_in[1];
  const float* V = (const float*)d_in[2];
  const int*   M = (const int*)d_in[3];
  float* Out  = (float*)d_out;
  float* Attn = Out + (size_t)B_ * H_ * S_ * D_;

  if (ws_size >= WS_NEED) {
    short* Qb = (short*)d_ws;
    short* Kf = Qb + (size_t)NSH;
    short* Vf = Kf + (size_t)NSH;
    unsigned long long* Bits = (unsigned long long*)(Vf + (size_t)NSH);
    const int pgrid = NSH / 8 / 256;  // 8192
    prep_q<<<dim3(pgrid), dim3(256), 0, stream>>>(Q, Qb);
    prep_k<<<dim3(pgrid), dim3(256), 0, stream>>>(K, Kf);
    prep_v<<<dim3(pgrid), dim3(256), 0, stream>>>(V, Vf);
    prep_m<<<dim3((unsigned)(NMW / 4)), dim3(256), 0, stream>>>(M, Bits);  // one wave per u64 word
    sdpa_main<<<dim3(B_ * H_ * (S_ / BM)), dim3(256), 0, stream>>>(Qb, Kf, Vf, Bits, Out, Attn);
  } else {
    sdpa_fallback<<<dim3(B_ * H_ * (S_ / BM)), dim3(256), 0, stream>>>(Q, K, V, M, Out, Attn);
  }
}

// Round 5
// 456.877 us; speedup vs baseline: 3.0495x; 1.8330x over previous
//
#include <hip/hip_runtime.h>

typedef __attribute__((ext_vector_type(8))) short short8;
typedef __attribute__((ext_vector_type(4))) short short4v;
typedef __attribute__((ext_vector_type(4))) float float4v;

#define B_ 4
#define H_ 16
#define S_ 2048
#define D_ 128
#define BM 64
#define NKT64 32          // 64-row K tiles (pass 1)
#define NKT32 64          // 32-row K/V subtiles (pass 2)

#define NSH (B_ * H_ * S_ * D_)                 // shorts per converted tensor
#define NMW ((size_t)B_ * 32 * S_)              // u64 mask words
#define WS_NEED (3ull * (unsigned long long)NSH * 2ull + (unsigned long long)NMW * 8ull)

// fold 1/sqrt(128) and log2(e) into Q: softmax in exp2 domain is identical
#define QSCALE (0.08838834764831845f * 1.4426950408889634f)

// fp32 -> bf16 bits, round-to-nearest-even (inputs are finite)
__device__ __forceinline__ short f2bf(float f) {
  unsigned u = __float_as_uint(f);
  u = (u + 0x7fffu + ((u >> 16) & 1u)) >> 16;
  return (short)u;
}

// global->LDS direct copy, 16B per lane; lds base must be wave-uniform,
// HW writes lane l at base + 16*l; global src is per-lane (include +l*16B).
__device__ __forceinline__ void gl16(const void* g, void* lds) {
  __builtin_amdgcn_global_load_lds(
      (const __attribute__((address_space(1))) unsigned int*)g,
      (__attribute__((address_space(3))) unsigned int*)lds, 16, 0, 0);
}

// ---------------- pre-pass: Q scaled bf16, row-major ----------------
__global__ void prep_q(const float* __restrict__ Qg, short* __restrict__ Qb) {
  size_t id = (size_t)blockIdx.x * 256 + threadIdx.x;  // one per 8 elements
  const float4v* src = (const float4v*)(Qg + id * 8);
  float4v a = src[0], b = src[1];
  short8 s;
  s[0] = f2bf(a[0] * QSCALE); s[1] = f2bf(a[1] * QSCALE);
  s[2] = f2bf(a[2] * QSCALE); s[3] = f2bf(a[3] * QSCALE);
  s[4] = f2bf(b[0] * QSCALE); s[5] = f2bf(b[1] * QSCALE);
  s[6] = f2bf(b[2] * QSCALE); s[7] = f2bf(b[3] * QSCALE);
  *((short8*)Qb + id) = s;
}

// ---------------- pre-pass: K in MFMA A-fragment order ----------------
// layout: [bh][kt64(32)][kf(4)][dc(4)][lane(64)][8], lane = g*16+c
// element = K[bh][kt64*64 + kf*16 + c][dc*32 + g*8 + e]
// (equivalently: contiguous 8KB per 32-row subtile kt32 = kt64*2 + (kf>>1))
__global__ void prep_k(const float* __restrict__ Kg, short* __restrict__ Kf) {
  size_t id = (size_t)blockIdx.x * 256 + threadIdx.x;
  int c  = (int)(id & 15);
  int g  = (int)((id >> 4) & 3);
  int dc = (int)((id >> 6) & 3);
  int kf = (int)((id >> 8) & 3);
  int kt = (int)((id >> 10) & 31);
  size_t bh = id >> 15;
  const float* src = Kg + ((bh * S_ + (size_t)(kt * 64 + kf * 16 + c)) * D_) + dc * 32 + g * 8;
  float4v a = *(const float4v*)src;
  float4v b = *(const float4v*)(src + 4);
  short8 s;
  s[0] = f2bf(a[0]); s[1] = f2bf(a[1]); s[2] = f2bf(a[2]); s[3] = f2bf(a[3]);
  s[4] = f2bf(b[0]); s[5] = f2bf(b[1]); s[6] = f2bf(b[2]); s[7] = f2bf(b[3]);
  *((short8*)Kf + id) = s;
}

// ---------------- pre-pass: V^T in MFMA A-fragment order, 32-row subtiles ----------------
// layout: [bh][kt32(64)][df(8)][lane(64)][8], lane = g*16+c
// element = V[bh][kt32*32 + g*8 + e][df*16 + c]
__global__ void prep_v(const float* __restrict__ Vg, short* __restrict__ Vf) {
  size_t id = (size_t)blockIdx.x * 256 + threadIdx.x;
  int c   = (int)(id & 15);
  int g   = (int)((id >> 4) & 3);
  int df  = (int)((id >> 6) & 7);
  int kt32= (int)((id >> 9) & 63);
  size_t bh = id >> 15;
  const float* src = Vg + (bh * S_ + (size_t)(kt32 * 32 + g * 8)) * D_ + df * 16 + c;
  short8 s;
#pragma unroll
  for (int e = 0; e < 8; ++e) s[e] = f2bf(src[(size_t)e * D_]);
  *((short8*)Vf + id) = s;
}

// ---------------- pre-pass: bit-pack mask via ballot ----------------
// Bits[b][kt64(32)][q(2048)] u64; bit j = (mask[b][q][kt64*64+j] != 0)
__global__ void prep_m(const int* __restrict__ Mg, unsigned long long* __restrict__ Bits) {
  int gw = blockIdx.x * 4 + (threadIdx.x >> 6);   // global wave id, 0..NMW-1
  int j  = threadIdx.x & 63;
  int kt = gw & 31;
  int q  = (gw >> 5) & (S_ - 1);
  int b  = gw >> 16;
  int m = Mg[((size_t)b * S_ + q) * S_ + kt * 64 + j];
  unsigned long long bal = __ballot(m != 0);
  if (j == 0) Bits[((size_t)b * 32 + kt) * S_ + q] = bal;
}

// ---------------- main: LDS-staged double-buffered 2-pass attention ----------------
__global__ __launch_bounds__(256, 4) void sdpa_main(
    const short* __restrict__ Qb, const short* __restrict__ Kfr,
    const short* __restrict__ Vfr, const unsigned long long* __restrict__ Bits,
    float* __restrict__ Og, float* __restrict__ Ag) {

  // region A (32KB): pass1 = K dbuf 2x16KB ; pass2 = K dbuf 2x8KB @0 + V dbuf 2x8KB @16384
  // region B (5120B): Ps[64][40] wave-private P transpose
  __shared__ __align__(16) char smem[32768 + 5120];
  short (*Ps)[40] = (short (*)[40])(smem + 32768);

  const int t = threadIdx.x;
  const int w = t >> 6;
  const int l = t & 63;
  const int g = l >> 4;
  const int c = l & 15;

  const int bid = blockIdx.x;
  const int qt = bid & 31;
  const int h  = (bid >> 5) & 15;
  const int b  = bid >> 9;

  const int qbase  = qt * BM;
  const int qrow_l = w * 16 + c;
  const int qrow   = qbase + qrow_l;

  const size_t bhOff = (size_t)(b * H_ + h) * (S_ * D_);
  const short* Qp  = Qb  + bhOff;
  const short* Kp  = Kfr + bhOff;
  const short* Vp  = Vfr + bhOff;
  const unsigned long long* Bp = Bits + (size_t)b * 32 * S_;
  const unsigned* Bu = (const unsigned*)Bits;
  float* Op = Og + bhOff;
  float* Ap = Ag + (size_t)(b * H_ + h) * ((size_t)S_ * S_);

  // per-lane Q fragments straight from global (already scaled bf16)
  short8 qf[4];
#pragma unroll
  for (int dc = 0; dc < 4; ++dc)
    qf[dc] = *(const short8*)(Qp + (size_t)qrow * D_ + dc * 32 + g * 8);

  // =============== pass 1: row sums of exp2(scores), K staged in LDS ===============
  // prologue: stage tile 0 into buf0 (16 chunks of 1KB; wave w takes w*4..w*4+3)
#pragma unroll
  for (int i = 0; i < 4; ++i) {
    int f = w * 4 + i;
    gl16(Kp + f * 512 + l * 8, smem + f * 1024);
  }
  __syncthreads();

  float ls0 = 0.f, ls1 = 0.f, ls2 = 0.f, ls3 = 0.f;
  int cur = 0;
  for (int kt = 0; kt < NKT64; ++kt) {
    if (kt < NKT64 - 1) {   // stage next tile into the other buffer
      const short* src = Kp + (size_t)(kt + 1) * 8192;
      char* dst = smem + (cur ^ 1) * 16384;
#pragma unroll
      for (int i = 0; i < 4; ++i) {
        int f = w * 4 + i;
        gl16(src + f * 512 + l * 8, dst + f * 1024);
      }
    }
    unsigned long long mb = Bp[(size_t)kt * S_ + qrow];
    const char* kb = smem + cur * 16384;

    float4v acc[4];
#pragma unroll
    for (int kf = 0; kf < 4; ++kf) acc[kf] = (float4v){0.f, 0.f, 0.f, 0.f};
#pragma unroll
    for (int kf = 0; kf < 4; ++kf) {
#pragma unroll
      for (int dc = 0; dc < 4; ++dc) {
        short8 af = *(const short8*)(kb + (kf * 4 + dc) * 1024 + l * 16);
        acc[kf] = __builtin_amdgcn_mfma_f32_16x16x32_bf16(af, qf[dc], acc[kf], 0, 0, 0);
      }
    }
    // lane holds S^T[k = kt*64 + kf*16 + g*4 + r][q = c] (log2 domain)
#pragma unroll
    for (int kf = 0; kf < 4; ++kf) {
      unsigned mg = (unsigned)(mb >> (kf * 16 + g * 4)) & 0xFu;
      float p0 = ((mg >> 0) & 1) ? __builtin_amdgcn_exp2f(acc[kf][0]) : 0.f;
      float p1 = ((mg >> 1) & 1) ? __builtin_amdgcn_exp2f(acc[kf][1]) : 0.f;
      float p2 = ((mg >> 2) & 1) ? __builtin_amdgcn_exp2f(acc[kf][2]) : 0.f;
      float p3 = ((mg >> 3) & 1) ? __builtin_amdgcn_exp2f(acc[kf][3]) : 0.f;
      if (kf == 0) ls0 += (p0 + p1) + (p2 + p3);
      else if (kf == 1) ls1 += (p0 + p1) + (p2 + p3);
      else if (kf == 2) ls2 += (p0 + p1) + (p2 + p3);
      else ls3 += (p0 + p1) + (p2 + p3);
    }
    __syncthreads();   // drains this wave's stage (vmcnt0) + everyone done reading kb
    cur ^= 1;
  }
  float lsum = (ls0 + ls1) + (ls2 + ls3);
  lsum += __shfl_xor(lsum, 16);
  lsum += __shfl_xor(lsum, 32);
  const float rl = (lsum > 0.f) ? (1.0f / lsum) : 0.f;

  // =============== pass 2: attention write + PV, K+V staged in LDS ===============
  // prologue: stage subtile 0 (K 8KB + V 8KB; wave w takes chunks {w, w+4})
#pragma unroll
  for (int i = 0; i < 2; ++i) {
    int f = w + 4 * i;
    gl16(Kp + f * 512 + l * 8, smem + f * 1024);
    gl16(Vp + f * 512 + l * 8, smem + 16384 + f * 1024);
  }
  __syncthreads();

  float4v acco[8];
#pragma unroll
  for (int df = 0; df < 8; ++df) acco[df] = (float4v){0.f, 0.f, 0.f, 0.f};

  cur = 0;
  for (int kt = 0; kt < NKT32; ++kt) {
    if (kt < NKT32 - 1) {
      const short* ks = Kp + (size_t)(kt + 1) * 4096;
      const short* vs = Vp + (size_t)(kt + 1) * 4096;
      char* kd = smem + (cur ^ 1) * 8192;
      char* vd = smem + 16384 + (cur ^ 1) * 8192;
#pragma unroll
      for (int i = 0; i < 2; ++i) {
        int f = w + 4 * i;
        gl16(ks + f * 512 + l * 8, kd + f * 1024);
        gl16(vs + f * 512 + l * 8, vd + f * 1024);
      }
    }
    unsigned mw = Bu[((size_t)(b * 32 + (kt >> 1)) * S_ + qrow) * 2 + (kt & 1)];
    const char* kb = smem + cur * 8192;
    const char* vb = smem + 16384 + cur * 8192;

    float4v acc[2];
#pragma unroll
    for (int kf = 0; kf < 2; ++kf) acc[kf] = (float4v){0.f, 0.f, 0.f, 0.f};
#pragma unroll
    for (int kf = 0; kf < 2; ++kf) {
#pragma unroll
      for (int dc = 0; dc < 4; ++dc) {
        short8 af = *(const short8*)(kb + (kf * 4 + dc) * 1024 + l * 16);
        acc[kf] = __builtin_amdgcn_mfma_f32_16x16x32_bf16(af, qf[dc], acc[kf], 0, 0, 0);
      }
    }

    // normalized probabilities: fp32 attention write + bf16 into Ps for PV
#pragma unroll
    for (int kf = 0; kf < 2; ++kf) {
      int k0 = kt * 32 + kf * 16 + g * 4;
      unsigned mg = (mw >> (kf * 16 + g * 4)) & 0xFu;
      float4v aw;
      short4v pb;
#pragma unroll
      for (int r = 0; r < 4; ++r) {
        float pn = ((mg >> r) & 1) ? __builtin_amdgcn_exp2f(acc[kf][r]) * rl : 0.f;
        aw[r] = pn;
        pb[r] = f2bf(pn);
      }
      __builtin_nontemporal_store(aw, (float4v*)(Ap + (size_t)qrow * S_ + k0));
      *(short4v*)&Ps[qrow_l][kf * 16 + g * 4] = pb;
    }

    // PV: O^T[d][q] += V^T[d][k] * P^T[k][q]; Ps roundtrip is wave-private
    {
      short8 pbf = *(const short8*)&Ps[qrow_l][g * 8];
#pragma unroll
      for (int df = 0; df < 8; ++df) {
        short8 vf = *(const short8*)(vb + df * 1024 + l * 16);
        acco[df] = __builtin_amdgcn_mfma_f32_16x16x32_bf16(vf, pbf, acco[df], 0, 0, 0);
      }
    }
    __syncthreads();
    cur ^= 1;
  }

#pragma unroll
  for (int df = 0; df < 8; ++df) {
    *(float4v*)(Op + (size_t)qrow * D_ + df * 16 + g * 4) = acco[df];
  }
}

// ================= fallback (round-1 kernel) if ws too small =================
#define LQK 136
#define LVT 72

__global__ __launch_bounds__(256, 3) void sdpa_fallback(
    const float* __restrict__ Qg, const float* __restrict__ Kg,
    const float* __restrict__ Vg, const int* __restrict__ Mg,
    float* __restrict__ Og, float* __restrict__ Ag) {

  __shared__ __align__(16) char smemf[17408 + 27648];
  short (*Ks)[LQK]  = (short (*)[LQK])(smemf);
  short (*Qs)[LQK]  = (short (*)[LQK])(smemf + 17408);
  short (*VTs)[LVT] = (short (*)[LVT])(smemf + 17408);
  short (*Psf)[LVT] = (short (*)[LVT])(smemf + 17408 + 18432);

  const int t = threadIdx.x;
  const int w = t >> 6;
  const int l = t & 63;
  const int g = l >> 4;
  const int c = l & 15;

  const int bid = blockIdx.x;
  const int qt = bid & 31;
  const int h  = (bid >> 5) & 15;
  const int b  = bid >> 9;

  const int qbase  = qt * BM;
  const int qrow_l = w * 16 + c;
  const int qrow   = qbase + qrow_l;

  const size_t bhOff = (size_t)(b * H_ + h) * (S_ * D_);
  const float* Qp = Qg + bhOff;
  const float* Kp = Kg + bhOff;
  const float* Vp = Vg + bhOff;
  const int*   Mp = Mg + (size_t)b * S_ * S_;
  float* Op = Og + bhOff;
  float* Ap = Ag + (size_t)(b * H_ + h) * ((size_t)S_ * S_);

#pragma unroll
  for (int i = 0; i < 8; ++i) {
    int idx = t + i * 256;
    int d4 = idx & 31, row = idx >> 5;
    float4v v = *(const float4v*)(Qp + (size_t)(qbase + row) * D_ + d4 * 4);
    short4v s;
    s[0] = f2bf(v[0] * QSCALE); s[1] = f2bf(v[1] * QSCALE);
    s[2] = f2bf(v[2] * QSCALE); s[3] = f2bf(v[3] * QSCALE);
    *(short4v*)&Qs[row][d4 * 4] = s;
  }
  __syncthreads();

  short8 qf[4];
#pragma unroll
  for (int dc = 0; dc < 4; ++dc)
    qf[dc] = *(const short8*)&Qs[qrow_l][dc * 32 + g * 8];

  float m_run = -1e30f, l_run = 0.f;
  for (int kt = 0; kt < 32; ++kt) {
    __syncthreads();
#pragma unroll
    for (int i = 0; i < 8; ++i) {
      int idx = t + i * 256;
      int d4 = idx & 31, row = idx >> 5;
      float4v v = *(const float4v*)(Kp + (size_t)(kt * 64 + row) * D_ + d4 * 4);
      short4v s;
      s[0] = f2bf(v[0]); s[1] = f2bf(v[1]); s[2] = f2bf(v[2]); s[3] = f2bf(v[3]);
      *(short4v*)&Ks[row][d4 * 4] = s;
    }
    __syncthreads();

    float4v acc[4];
#pragma unroll
    for (int kf = 0; kf < 4; ++kf) acc[kf] = (float4v){0.f, 0.f, 0.f, 0.f};
#pragma unroll
    for (int kf = 0; kf < 4; ++kf) {
#pragma unroll
      for (int dc = 0; dc < 4; ++dc) {
        short8 af = *(const short8*)&Ks[kf * 16 + c][dc * 32 + g * 8];
        acc[kf] = __builtin_amdgcn_mfma_f32_16x16x32_bf16(af, qf[dc], acc[kf], 0, 0, 0);
      }
    }

    float sv[4][4];
    float tmax = -1e30f;
#pragma unroll
    for (int kf = 0; kf < 4; ++kf) {
      int k0 = kt * 64 + kf * 16 + g * 4;
      const int4 mv = *(const int4*)(Mp + (size_t)qrow * S_ + k0);
      int mr[4] = {mv.x, mv.y, mv.z, mv.w};
#pragma unroll
      for (int r = 0; r < 4; ++r) {
        float x = acc[kf][r];
        x = (mr[r] == 0) ? -1e9f : x;
        sv[kf][r] = x;
        tmax = fmaxf(tmax, x);
      }
    }
    tmax = fmaxf(tmax, __shfl_xor(tmax, 16));
    tmax = fmaxf(tmax, __shfl_xor(tmax, 32));
    float newm = fmaxf(m_run, tmax);
    float tsum = 0.f;
#pragma unroll
    for (int kf = 0; kf < 4; ++kf)
#pragma unroll
      for (int r = 0; r < 4; ++r)
        tsum += __builtin_amdgcn_exp2f(sv[kf][r] - newm);
    tsum += __shfl_xor(tsum, 16);
    tsum += __shfl_xor(tsum, 32);
    l_run = l_run * __builtin_amdgcn_exp2f(m_run - newm) + tsum;
    m_run = newm;
  }

  const float rl = 1.0f / l_run;

  float4v acco[8];
#pragma unroll
  for (int df = 0; df < 8; ++df) acco[df] = (float4v){0.f, 0.f, 0.f, 0.f};

  for (int kt = 0; kt < 32; ++kt) {
    __syncthreads();
#pragma unroll
    for (int i = 0; i < 8; ++i) {
      int idx = t + i * 256;
      int d4 = idx & 31, row = idx >> 5;
      float4v v = *(const float4v*)(Kp + (size_t)(kt * 64 + row) * D_ + d4 * 4);
      short4v s;
      s[0] = f2bf(v[0]); s[1] = f2bf(v[1]); s[2] = f2bf(v[2]); s[3] = f2bf(v[3]);
      *(short4v*)&Ks[row][d4 * 4] = s;
    }
#pragma unroll
    for (int i = 0; i < 8; ++i) {
      int idx = t + i * 256;
      int d = idx & 127, kq = idx >> 7;
      const float* vp = Vp + (size_t)(kt * 64 + kq * 4) * D_ + d;
      short4v s;
      s[0] = f2bf(vp[0]); s[1] = f2bf(vp[D_]); s[2] = f2bf(vp[2 * D_]); s[3] = f2bf(vp[3 * D_]);
      *(short4v*)&VTs[d][kq * 4] = s;
    }
    __syncthreads();

    float4v acc[4];
#pragma unroll
    for (int kf = 0; kf < 4; ++kf) acc[kf] = (float4v){0.f, 0.f, 0.f, 0.f};
#pragma unroll
    for (int kf = 0; kf < 4; ++kf) {
#pragma unroll
      for (int dc = 0; dc < 4; ++dc) {
        short8 af = *(const short8*)&Ks[kf * 16 + c][dc * 32 + g * 8];
        acc[kf] = __builtin_amdgcn_mfma_f32_16x16x32_bf16(af, qf[dc], acc[kf], 0, 0, 0);
      }
    }

#pragma unroll
    for (int kf = 0; kf < 4; ++kf) {
      int k0 = kt * 64 + kf * 16 + g * 4;
      const int4 mv = *(const int4*)(Mp + (size_t)qrow * S_ + k0);
      int mr[4] = {mv.x, mv.y, mv.z, mv.w};
      float4v aw;
      short4v pb;
#pragma unroll
      for (int r = 0; r < 4; ++r) {
        float x = acc[kf][r];
        x = (mr[r] == 0) ? -1e9f : x;
        float pn = __builtin_amdgcn_exp2f(x - m_run) * rl;
        aw[r] = pn;
        pb[r] = f2bf(pn);
      }
      __builtin_nontemporal_store(aw, (float4v*)(Ap + (size_t)qrow * S_ + k0));
      *(short4v*)&Psf[qrow_l][kf * 16 + g * 4] = pb;
    }

#pragma unroll
    for (int kc = 0; kc < 2; ++kc) {
      short8 pbf = *(const short8*)&Psf[qrow_l][kc * 32 + g * 8];
#pragma unroll
      for (int df = 0; df < 8; ++df) {
        short8 vf = *(const short8*)&VTs[df * 16 + c][kc * 32 + g * 8];
        acco[df] = __builtin_amdgcn_mfma_f32_16x16x32_bf16(vf, pbf, acco[df], 0, 0, 0);
      }
    }
  }

#pragma unroll
  for (int df = 0; df < 8; ++df) {
    *(float4v*)(Op + (size_t)qrow * D_ + df * 16 + g * 4) = acco[df];
  }
}

extern "C" void kernel_launch(void* const* d_in, const int* in_sizes, int n_in,
                              void* d_out, int out_size, void* d_ws, size_t ws_size,
                              hipStream_t stream) {
  const float* Q = (const float*)d_in[0];
  const float* K = (const float*)d_in[1];
  const float* V = (const float*)d_in[2];
  const int*   M = (const int*)d_in[3];
  float* Out  = (float*)d_out;
  float* Attn = Out + (size_t)B_ * H_ * S_ * D_;

  if (ws_size >= WS_NEED) {
    short* Qb = (short*)d_ws;
    short* Kf = Qb + (size_t)NSH;
    short* Vf = Kf + (size_t)NSH;
    unsigned long long* Bits = (unsigned long long*)(Vf + (size_t)NSH);
    const int pgrid = NSH / 8 / 256;  // 8192
    prep_q<<<dim3(pgrid), dim3(256), 0, stream>>>(Q, Qb);
    prep_k<<<dim3(pgrid), dim3(256), 0, stream>>>(K, Kf);
    prep_v<<<dim3(pgrid), dim3(256), 0, stream>>>(V, Vf);
    prep_m<<<dim3((unsigned)(NMW / 4)), dim3(256), 0, stream>>>(M, Bits);  // one wave per u64 word
    sdpa_main<<<dim3(B_ * H_ * (S_ / BM)), dim3(256), 0, stream>>>(Qb, Kf, Vf, Bits, Out, Attn);
  } else {
    sdpa_fallback<<<dim3(B_ * H_ * (S_ / BM)), dim3(256), 0, stream>>>(Q, K, V, M, Out, Attn);
  }
}